// Round 1
// baseline (421.519 us; speedup 1.0000x reference)
//
#include <hip/hip_runtime.h>
#include <hip/hip_fp16.h>

// out[b,o] = sum_{i,n} x[b,i]*noise[b,n]*hW[i*512+o,n]      (main, branch 0, z=0..15)
//          + sum_{i,n} px[b,i]*noise[b,n]*pW[i*512+o,n]     (main, branch 1, z=16..31)
//          + sum_i x[b,i]*hb[i*512+o] (+ prior)             (E1: extra K=32 MFMA after loop)
//          + sum_n noise[b,n]*(hW[MAIN_D+o,n]+pW[...,n])    (E2: macro 33 on z%16==0)
//          + hb[MAIN_D+o] + pb[MAIN_D+o]                    (init kernel)
//
// R4: o-tile 128->64, noise fragments loaded direct from global (no LDS overlay)
//     -> LDS 88KB -> 54KB -> 2 blocks/CU (16 waves, 2 independent barrier groups).
//     Per-CU/macro traffic identical to R3; only overlap structure changes.

#define MAIN_D (512*512)

typedef _Float16 half8 __attribute__((ext_vector_type(8)));
typedef float floatx4 __attribute__((ext_vector_type(4)));

static __device__ __forceinline__ unsigned pk2(float a, float b) {
    union { __half2 h; unsigned u; } c;
    c.h = __float22half2_rn(make_float2(a, b));
    return c.u;
}

static __device__ __forceinline__ half8 mk8(float4 a, float4 b) {
    union { uint4 u; half8 h; } r;
    r.u = make_uint4(pk2(a.x, a.y), pk2(a.z, a.w), pk2(b.x, b.y), pk2(b.z, b.w));
    return r.h;
}

// ---- init: out[b,o] = hb[MAIN_D+o] + pb[MAIN_D+o] ----
__global__ __launch_bounds__(256) void init_kernel(
    const float* __restrict__ hb, const float* __restrict__ pb,
    float* __restrict__ out)
{
    const int idx = blockIdx.x * 256 + threadIdx.x;   // 65536 threads x float4
    const int o4 = (idx * 4) & 511;
    float4 v;
    v.x = hb[MAIN_D + o4 + 0] + pb[MAIN_D + o4 + 0];
    v.y = hb[MAIN_D + o4 + 1] + pb[MAIN_D + o4 + 1];
    v.z = hb[MAIN_D + o4 + 2] + pb[MAIN_D + o4 + 2];
    v.w = hb[MAIN_D + o4 + 3] + pb[MAIN_D + o4 + 3];
    *(float4*)(out + idx * 4) = v;
}

// ---- main: 512 blocks x 512 threads (8 waves, 4m x 2n of 64x32 tiles) ----
__global__ __launch_bounds__(512, 4) void main_gemm(
    const float* __restrict__ x, const float* __restrict__ px,
    const float* __restrict__ noise,
    const float* __restrict__ hW, const float* __restrict__ hb,
    const float* __restrict__ pW, const float* __restrict__ pb,
    float* __restrict__ out)
{
    // W tile double buffer [2][64 o][136 halfs] (cols 0..127 = n). 34816 B.
    __shared__ __attribute__((aligned(16))) _Float16 Bl[2][64 * 136];
    __shared__ __attribute__((aligned(16))) _Float16 xhl[256 * 40];  // x [b][i] half

    const int t = threadIdx.x;
    // sibling-swizzled decode: the 2 blocks sharing a W slab are 8 apart in
    // linear index (same XCD under round-robin dispatch) -> L2 slab sharing.
    const int lin  = blockIdx.x;            // 0..511
    const int s    = (lin >> 3) & 1;        // b-tile (sibling id)
    const int g    = ((lin >> 4) << 3) | (lin & 7);   // 0..255 slab group
    const int y    = g & 7;                 // o-tile 0..7
    const int z    = g >> 3;                // 0..31: branch*16 + i-chunk
    const int b0   = s * 256;
    const int o0   = y * 64;
    const int branch = z >> 4;
    const int ic0  = (z & 15) * 32;
    const float* __restrict__ xsrc = branch ? px : x;
    const float* __restrict__ Ws   = branch ? pW : hW;
    const float* __restrict__ bias = branch ? pb : hb;
    const int nmacro = ((z & 15) == 0) ? 33 : 32;

    const int lane = t & 63;
    const int w    = t >> 6;
    const int wm64 = (w >> 1) * 64;         // 0,64,128,192
    const int wn32 = (w & 1) * 32;          // 0,32
    const int quad = lane >> 4;
    const int l16  = lane & 15;

    // ---- stage x tile 256b x 32i -> half, stride 40 ----
#pragma unroll
    for (int k = 0; k < 4; ++k) {
        int idx = k * 512 + t;              // 0..2047
        int bb = idx >> 3, c = (idx & 7) * 4;
        float4 v = *(const float4*)(xsrc + (b0 + bb) * 512 + ic0 + c);
        *(unsigned*)&xhl[bb * 40 + c]     = pk2(v.x, v.y);
        *(unsigned*)&xhl[bb * 40 + c + 2] = pk2(v.z, v.w);
    }

    // ---- noise A-fragments direct from global (L2-resident, prologue-only) ----
    // nzf[mf][q][j] = noise_h[b0+wm64+mf*16+l16][q*32+quad*8+j]
    half8 nzf[4][4];
#pragma unroll
    for (int mf = 0; mf < 4; ++mf)
#pragma unroll
        for (int q = 0; q < 4; ++q) {
            const float* np = noise + (long)(b0 + wm64 + mf * 16 + l16) * 128
                            + q * 32 + quad * 8;
            nzf[mf][q] = mk8(*(const float4*)np, *(const float4*)(np + 4));
        }

    floatx4 acc[4][2];
#pragma unroll
    for (int a = 0; a < 4; ++a)
#pragma unroll
        for (int b = 0; b < 2; ++b) acc[a][b] = (floatx4)0.0f;

    // W slab staging: 32KB slab = 64 rows x 128 floats; thread handles 2 chunks
    // of 8 contiguous floats -> one 16B LDS write each (conflict-free minimum).
    float4 wa[2], wb[2];
    {
        const float* p = Ws + (long)(ic0 * 512 + o0) * 128;
#pragma unroll
        for (int j = 0; j < 2; ++j) {
            int c = j * 512 + t;
            int off = (c >> 4) * 128 + (c & 15) * 8;
            wa[j] = *(const float4*)(p + off);
            wb[j] = *(const float4*)(p + off + 4);
        }
    }
    // no barrier needed here: first macro's __syncthreads covers xhl staging;
    // nzf/wa/wb are own-thread register data.

    for (int m = 0; m < nmacro; ++m) {
        _Float16* buf = &Bl[m & 1][0];
        // write staged regs -> current buffer (ds_write_b128, lane-consecutive)
#pragma unroll
        for (int j = 0; j < 2; ++j) {
            int c = j * 512 + t;
            int row = c >> 4, col8 = (c & 15) * 8;
            *(uint4*)&buf[row * 136 + col8] = make_uint4(
                pk2(wa[j].x, wa[j].y), pk2(wa[j].z, wa[j].w),
                pk2(wb[j].x, wb[j].y), pk2(wb[j].z, wb[j].w));
        }
        __syncthreads();                     // one barrier per macro (dbuf)
        if (m + 1 < nmacro) {                // prefetch next slab (in flight over MFMA)
            long rb = (m + 1 < 32) ? (long)((ic0 + m + 1) * 512 + o0)
                                   : (long)(MAIN_D + o0);
            const float* p = Ws + rb * 128;
#pragma unroll
            for (int j = 0; j < 2; ++j) {
                int c = j * 512 + t;
                int off = (c >> 4) * 128 + (c & 15) * 8;
                wa[j] = *(const float4*)(p + off);
                wb[j] = *(const float4*)(p + off + 4);
            }
        }
        const bool isE2 = (m >= 32);
        _Float16 xs[4];
        if (!isE2) {
#pragma unroll
            for (int mf = 0; mf < 4; ++mf)
                xs[mf] = xhl[(wm64 + mf * 16 + l16) * 40 + m];
        }
#pragma unroll
        for (int q = 0; q < 4; ++q) {
            half8 bfr[2], afr[4];
#pragma unroll
            for (int nf = 0; nf < 2; ++nf)
                bfr[nf] = *(half8*)&buf[(wn32 + nf * 16 + l16) * 136 + q * 32 + quad * 8];
#pragma unroll
            for (int mf = 0; mf < 4; ++mf) {
                if (isE2) afr[mf] = nzf[mf][q];
                else {
                    half8 xv;
#pragma unroll
                    for (int j = 0; j < 8; ++j) xv[j] = xs[mf];
                    afr[mf] = nzf[mf][q] * xv;
                }
            }
            __builtin_amdgcn_s_setprio(1);   // 2 independent blocks/CU -> role diversity
#pragma unroll
            for (int mf = 0; mf < 4; ++mf)
#pragma unroll
                for (int nf = 0; nf < 2; ++nf)
                    acc[mf][nf] = __builtin_amdgcn_mfma_f32_16x16x32_f16(
                        afr[mf], bfr[nf], acc[mf][nf], 0, 0, 0);
            __builtin_amdgcn_s_setprio(0);
        }
    }

    // ---- E1: bias GEMM step, K=32 (A = x tile in LDS) ----
    __syncthreads();
    {
        const int oo = t >> 3, kh = (t & 7) * 4;   // 64 o-rows x 32 k
        float tmp[4];
#pragma unroll
        for (int j = 0; j < 4; ++j)
            tmp[j] = bias[(long)(ic0 + kh + j) * 512 + o0 + oo];
        *(uint2*)&Bl[0][oo * 136 + kh] = make_uint2(
            pk2(tmp[0], tmp[1]), pk2(tmp[2], tmp[3]));
    }
    __syncthreads();
    {
        half8 afr[4], bfr[2];
#pragma unroll
        for (int mf = 0; mf < 4; ++mf)
            afr[mf] = *(half8*)&xhl[(wm64 + mf * 16 + l16) * 40 + quad * 8];
#pragma unroll
        for (int nf = 0; nf < 2; ++nf)
            bfr[nf] = *(half8*)&Bl[0][(wn32 + nf * 16 + l16) * 136 + quad * 8];
#pragma unroll
        for (int mf = 0; mf < 4; ++mf)
#pragma unroll
            for (int nf = 0; nf < 2; ++nf)
                acc[mf][nf] = __builtin_amdgcn_mfma_f32_16x16x32_f16(
                    afr[mf], bfr[nf], acc[mf][nf], 0, 0, 0);
    }

    // ---- split-K accumulate (C/D: row=quad*4+r, col=l16; verified R1/R2) ----
#pragma unroll
    for (int mf = 0; mf < 4; ++mf)
#pragma unroll
        for (int nf = 0; nf < 2; ++nf)
#pragma unroll
            for (int r = 0; r < 4; ++r) {
                int row = b0 + wm64 + mf * 16 + quad * 4 + r;
                int col = o0 + wn32 + nf * 16 + l16;
                atomicAdd(out + row * 512 + col, acc[mf][nf][r]);
            }
}

extern "C" void kernel_launch(void* const* d_in, const int* in_sizes, int n_in,
                              void* d_out, int out_size, void* d_ws, size_t ws_size,
                              hipStream_t stream) {
    const float* x  = (const float*)d_in[0];
    const float* px = (const float*)d_in[1];
    const float* nz = (const float*)d_in[2];
    const float* hW = (const float*)d_in[3];
    const float* hb = (const float*)d_in[4];
    const float* pW = (const float*)d_in[5];
    const float* pb = (const float*)d_in[6];
    float* out = (float*)d_out;

    hipLaunchKernelGGL(init_kernel, dim3(256), dim3(256), 0, stream, hb, pb, out);
    hipLaunchKernelGGL(main_gemm, dim3(512), dim3(512), 0, stream,
                       x, px, nz, hW, hb, pW, pb, out);
}

// Round 2
// 342.877 us; speedup vs baseline: 1.2294x; 1.2294x over previous
//
#include <hip/hip_runtime.h>
#include <hip/hip_fp16.h>

// out[b,o] = sum_{i,n} x[b,i]*noise[b,n]*hW[i*512+o,n]      (main, branch 0, z=0..15)
//          + sum_{i,n} px[b,i]*noise[b,n]*pW[i*512+o,n]     (main, branch 1, z=16..31)
//          + sum_i x[b,i]*hb[i*512+o] (+ prior)             (E1: extra K=32 MFMA after loop)
//          + sum_n noise[b,n]*(hW[MAIN_D+o,n]+pW[...,n])    (E2: macro 33 on z%16==0)
//          + hb[MAIN_D+o] + pb[MAIN_D+o]                    (init kernel)
//
// R5: b-tile split (not o-split): block = 128b x 128o, 512 blocks, 2 blocks/CU.
//     Slab-group structure IDENTICAL to R3 (128 groups x 64KB slabs) -> preserves
//     L2 locality that R4's o-split destroyed (FETCH 137->421MB). 4 siblings per
//     slab, consecutive on one XCD. LDS 79872B -> 2 blocks/CU, 16 waves, two
//     independent barrier groups overlap MFMA vs stage/LDS phases.

#define MAIN_D (512*512)

typedef _Float16 half8 __attribute__((ext_vector_type(8)));
typedef float floatx4 __attribute__((ext_vector_type(4)));

static __device__ __forceinline__ unsigned pk2(float a, float b) {
    union { __half2 h; unsigned u; } c;
    c.h = __float22half2_rn(make_float2(a, b));
    return c.u;
}

static __device__ __forceinline__ half8 mk8(float4 a, float4 b) {
    union { uint4 u; half8 h; } r;
    r.u = make_uint4(pk2(a.x, a.y), pk2(a.z, a.w), pk2(b.x, b.y), pk2(b.z, b.w));
    return r.h;
}

// ---- init: out[b,o] = hb[MAIN_D+o] + pb[MAIN_D+o] ----
__global__ __launch_bounds__(256) void init_kernel(
    const float* __restrict__ hb, const float* __restrict__ pb,
    float* __restrict__ out)
{
    const int idx = blockIdx.x * 256 + threadIdx.x;   // 65536 threads x float4
    const int o4 = (idx * 4) & 511;
    float4 v;
    v.x = hb[MAIN_D + o4 + 0] + pb[MAIN_D + o4 + 0];
    v.y = hb[MAIN_D + o4 + 1] + pb[MAIN_D + o4 + 1];
    v.z = hb[MAIN_D + o4 + 2] + pb[MAIN_D + o4 + 2];
    v.w = hb[MAIN_D + o4 + 3] + pb[MAIN_D + o4 + 3];
    *(float4*)(out + idx * 4) = v;
}

// ---- main: 512 blocks x 512 threads (8 waves, 4m x 2n of 32x64 tiles) ----
__global__ __launch_bounds__(512, 4) void main_gemm(
    const float* __restrict__ x, const float* __restrict__ px,
    const float* __restrict__ noise,
    const float* __restrict__ hW, const float* __restrict__ hb,
    const float* __restrict__ pW, const float* __restrict__ pb,
    float* __restrict__ out)
{
    // W tile double buffer [2][128 o][136 halfs] (cols 0..127 = n). 69632 B.
    __shared__ __attribute__((aligned(16))) _Float16 Bl[2][128 * 136];
    __shared__ __attribute__((aligned(16))) _Float16 xhl[128 * 40];  // x [b][i] half

    const int t = threadIdx.x;
    // sibling-swizzled decode: the 4 blocks sharing a W slab are 8 apart in
    // linear index (same XCD under round-robin dispatch, consecutive XCD slots)
    // -> L2 slab sharing, 4-way reuse.
    const int lin  = blockIdx.x;            // 0..511
    const int s    = (lin >> 3) & 3;        // b-tile (sibling id 0..3)
    const int g    = ((lin >> 5) << 3) | (lin & 7);   // 0..127 slab group
    const int z    = g >> 2;                // 0..31: branch*16 + i-chunk
    const int y    = g & 3;                 // o-tile
    const int b0   = s * 128;
    const int o0   = y * 128;
    const int branch = z >> 4;
    const int ic0  = (z & 15) * 32;
    const float* __restrict__ xsrc = branch ? px : x;
    const float* __restrict__ Ws   = branch ? pW : hW;
    const float* __restrict__ bias = branch ? pb : hb;
    const int nmacro = ((z & 15) == 0) ? 33 : 32;

    const int lane = t & 63;
    const int w    = t >> 6;
    const int wm32 = (w >> 1) * 32;         // 0,32,64,96
    const int wn64 = (w & 1) * 64;          // 0,64
    const int quad = lane >> 4;
    const int l16  = lane & 15;

    // ---- stage x tile 128b x 32i -> half, stride 40 ----
#pragma unroll
    for (int k = 0; k < 2; ++k) {
        int idx = k * 512 + t;              // 0..1023
        int bb = idx >> 3, c = (idx & 7) * 4;
        float4 v = *(const float4*)(xsrc + (b0 + bb) * 512 + ic0 + c);
        *(unsigned*)&xhl[bb * 40 + c]     = pk2(v.x, v.y);
        *(unsigned*)&xhl[bb * 40 + c + 2] = pk2(v.z, v.w);
    }

    // ---- noise A-fragments direct from global (L2-resident, prologue-only) ----
    // nzf[mf][q][j] = noise_h[b0+wm32+mf*16+l16][q*32+quad*8+j]
    half8 nzf[2][4];
#pragma unroll
    for (int mf = 0; mf < 2; ++mf)
#pragma unroll
        for (int q = 0; q < 4; ++q) {
            const float* np = noise + (long)(b0 + wm32 + mf * 16 + l16) * 128
                            + q * 32 + quad * 8;
            nzf[mf][q] = mk8(*(const float4*)np, *(const float4*)(np + 4));
        }

    floatx4 acc[2][4];
#pragma unroll
    for (int a = 0; a < 2; ++a)
#pragma unroll
        for (int b = 0; b < 4; ++b) acc[a][b] = (floatx4)0.0f;

    // W slab staging: 64KB slab = 128 rows x 128 floats; thread handles 4 chunks
    // of 8 contiguous floats -> one 16B LDS write each (conflict-free minimum).
    float4 wa[4], wb[4];
    {
        const float* p = Ws + (long)(ic0 * 512 + o0) * 128;
#pragma unroll
        for (int j = 0; j < 4; ++j) {
            int c = j * 512 + t;
            int off = (c >> 4) * 128 + (c & 15) * 8;
            wa[j] = *(const float4*)(p + off);
            wb[j] = *(const float4*)(p + off + 4);
        }
    }
    // no barrier needed here: first macro's __syncthreads covers xhl staging;
    // nzf/wa/wb are own-thread register data.

    for (int m = 0; m < nmacro; ++m) {
        _Float16* buf = &Bl[m & 1][0];
        // write staged regs -> current buffer (ds_write_b128, lane-consecutive)
#pragma unroll
        for (int j = 0; j < 4; ++j) {
            int c = j * 512 + t;
            int row = c >> 4, col8 = (c & 15) * 8;
            *(uint4*)&buf[row * 136 + col8] = make_uint4(
                pk2(wa[j].x, wa[j].y), pk2(wa[j].z, wa[j].w),
                pk2(wb[j].x, wb[j].y), pk2(wb[j].z, wb[j].w));
        }
        __syncthreads();                     // one barrier per macro (dbuf)
        if (m + 1 < nmacro) {                // prefetch next slab (in flight over MFMA)
            long rb = (m + 1 < 32) ? (long)((ic0 + m + 1) * 512 + o0)
                                   : (long)(MAIN_D + o0);
            const float* p = Ws + rb * 128;
#pragma unroll
            for (int j = 0; j < 4; ++j) {
                int c = j * 512 + t;
                int off = (c >> 4) * 128 + (c & 15) * 8;
                wa[j] = *(const float4*)(p + off);
                wb[j] = *(const float4*)(p + off + 4);
            }
        }
        const bool isE2 = (m >= 32);
        _Float16 xs[2];
        if (!isE2) {
#pragma unroll
            for (int mf = 0; mf < 2; ++mf)
                xs[mf] = xhl[(wm32 + mf * 16 + l16) * 40 + m];
        }
#pragma unroll
        for (int q = 0; q < 4; ++q) {
            half8 bfr[4], afr[2];
#pragma unroll
            for (int nf = 0; nf < 4; ++nf)
                bfr[nf] = *(half8*)&buf[(wn64 + nf * 16 + l16) * 136 + q * 32 + quad * 8];
#pragma unroll
            for (int mf = 0; mf < 2; ++mf) {
                if (isE2) afr[mf] = nzf[mf][q];
                else {
                    half8 xv;
#pragma unroll
                    for (int j = 0; j < 8; ++j) xv[j] = xs[mf];
                    afr[mf] = nzf[mf][q] * xv;
                }
            }
            __builtin_amdgcn_s_setprio(1);   // 2 independent blocks/CU -> role diversity
#pragma unroll
            for (int mf = 0; mf < 2; ++mf)
#pragma unroll
                for (int nf = 0; nf < 4; ++nf)
                    acc[mf][nf] = __builtin_amdgcn_mfma_f32_16x16x32_f16(
                        afr[mf], bfr[nf], acc[mf][nf], 0, 0, 0);
            __builtin_amdgcn_s_setprio(0);
        }
    }

    // ---- E1: bias GEMM step, K=32 (A = x tile in LDS) ----
    __syncthreads();
    {
        const int oo = t >> 2, kh = (t & 3) * 8;   // 128 o-rows x 32 k
        float tmp[8];
#pragma unroll
        for (int j = 0; j < 8; ++j)
            tmp[j] = bias[(long)(ic0 + kh + j) * 512 + o0 + oo];
        *(uint4*)&Bl[0][oo * 136 + kh] = make_uint4(
            pk2(tmp[0], tmp[1]), pk2(tmp[2], tmp[3]),
            pk2(tmp[4], tmp[5]), pk2(tmp[6], tmp[7]));
    }
    __syncthreads();
    {
        half8 afr[2], bfr[4];
#pragma unroll
        for (int mf = 0; mf < 2; ++mf)
            afr[mf] = *(half8*)&xhl[(wm32 + mf * 16 + l16) * 40 + quad * 8];
#pragma unroll
        for (int nf = 0; nf < 4; ++nf)
            bfr[nf] = *(half8*)&Bl[0][(wn64 + nf * 16 + l16) * 136 + quad * 8];
#pragma unroll
        for (int mf = 0; mf < 2; ++mf)
#pragma unroll
            for (int nf = 0; nf < 4; ++nf)
                acc[mf][nf] = __builtin_amdgcn_mfma_f32_16x16x32_f16(
                    afr[mf], bfr[nf], acc[mf][nf], 0, 0, 0);
    }

    // ---- split-K accumulate (C/D: row=quad*4+r, col=l16; verified R1/R2) ----
#pragma unroll
    for (int mf = 0; mf < 2; ++mf)
#pragma unroll
        for (int nf = 0; nf < 4; ++nf)
#pragma unroll
            for (int r = 0; r < 4; ++r) {
                int row = b0 + wm32 + mf * 16 + quad * 4 + r;
                int col = o0 + wn64 + nf * 16 + l16;
                atomicAdd(out + row * 512 + col, acc[mf][nf][r]);
            }
}

extern "C" void kernel_launch(void* const* d_in, const int* in_sizes, int n_in,
                              void* d_out, int out_size, void* d_ws, size_t ws_size,
                              hipStream_t stream) {
    const float* x  = (const float*)d_in[0];
    const float* px = (const float*)d_in[1];
    const float* nz = (const float*)d_in[2];
    const float* hW = (const float*)d_in[3];
    const float* hb = (const float*)d_in[4];
    const float* pW = (const float*)d_in[5];
    const float* pb = (const float*)d_in[6];
    float* out = (float*)d_out;

    hipLaunchKernelGGL(init_kernel, dim3(256), dim3(256), 0, stream, hb, pb, out);
    hipLaunchKernelGGL(main_gemm, dim3(512), dim3(512), 0, stream,
                       x, px, nz, hW, hb, pW, pb, out);
}

// Round 3
// 314.834 us; speedup vs baseline: 1.3389x; 1.0891x over previous
//
#include <hip/hip_runtime.h>
#include <hip/hip_fp16.h>

// out[b,o] = sum_{i,n} x[b,i]*noise[b,n]*hW[i*512+o,n]      (main, branch 0, z=0..15)
//          + sum_{i,n} px[b,i]*noise[b,n]*pW[i*512+o,n]     (main, branch 1, z=16..31)
//          + sum_i x[b,i]*hb[i*512+o] (+ prior)             (E1: extra K=32 MFMA after loop)
//          + sum_n noise[b,n]*(hW[MAIN_D+o,n]+pW[...,n])    (E2: macro 33 on z%16==0)
//          + hb[MAIN_D+o] + pb[MAIN_D+o]                    (folded into reduce kernel)
//
// R6: exact R3 geometry (256 blocks x 256b x 128o, 1 block/CU — best measured) but
//     atomic-free epilogue: each block owns a unique (z, s, y) region -> plain
//     stores into ws[z][512][512] (32MB workspace), then a reduce kernel sums the
//     32 slices + bias. Isolates the cost of the 8.4M-atomicAdd epilogue vs R3.

#define MAIN_D (512*512)

typedef _Float16 half8 __attribute__((ext_vector_type(8)));
typedef float floatx4 __attribute__((ext_vector_type(4)));

static __device__ __forceinline__ unsigned pk2(float a, float b) {
    union { __half2 h; unsigned u; } c;
    c.h = __float22half2_rn(make_float2(a, b));
    return c.u;
}

// ---- reduce: out[b,o] = hb[MAIN_D+o] + pb[MAIN_D+o] + sum_z ws[z][b][o] ----
__global__ __launch_bounds__(256) void reduce_kernel(
    const float* __restrict__ ws,
    const float* __restrict__ hb, const float* __restrict__ pb,
    float* __restrict__ out)
{
    const int idx = blockIdx.x * 256 + threadIdx.x;   // 65536 threads x float4
    const int o4 = (idx * 4) & 511;
    float4 acc;
    acc.x = hb[MAIN_D + o4 + 0] + pb[MAIN_D + o4 + 0];
    acc.y = hb[MAIN_D + o4 + 1] + pb[MAIN_D + o4 + 1];
    acc.z = hb[MAIN_D + o4 + 2] + pb[MAIN_D + o4 + 2];
    acc.w = hb[MAIN_D + o4 + 3] + pb[MAIN_D + o4 + 3];
#pragma unroll
    for (int zz = 0; zz < 32; ++zz) {
        float4 v = *(const float4*)(ws + (long)zz * (512 * 512) + idx * 4);
        acc.x += v.x; acc.y += v.y; acc.z += v.z; acc.w += v.w;
    }
    *(float4*)(out + idx * 4) = acc;
}

// ---- main: 256 blocks x 512 threads (8 waves, 4m x 2n of 64x64 tiles) ----
__global__ __launch_bounds__(512, 2) void main_gemm(
    const float* __restrict__ x, const float* __restrict__ px,
    const float* __restrict__ noise,
    const float* __restrict__ hW, const float* __restrict__ hb,
    const float* __restrict__ pW, const float* __restrict__ pb,
    float* __restrict__ ws)
{
    // W tile double buffer [2][128 o][136 halfs] (cols 0..127 = n). 69632 B.
    // Prologue overlay: noise staging [256 b][136 halfs].
    __shared__ __attribute__((aligned(16))) _Float16 Bl[2][128 * 136];
    __shared__ __attribute__((aligned(16))) _Float16 xhl[256 * 40];  // x [b][i] half

    const int t = threadIdx.x;
    // sibling-swizzled decode: the 2 blocks sharing a W slab are 8 apart in
    // linear index (same XCD under round-robin dispatch) -> L2 slab sharing.
    const int lin  = blockIdx.x;            // 0..255
    const int s    = (lin >> 3) & 1;        // b-tile (sibling id)
    const int g    = ((lin >> 4) << 3) | (lin & 7);   // 0..127 slab group
    const int z    = g >> 2;                // 0..31: branch*16 + i-chunk
    const int y    = g & 3;                 // o-tile
    const int b0   = s * 256;
    const int o0   = y * 128;
    const int branch = z >> 4;
    const int ic0  = (z & 15) * 32;
    const float* __restrict__ xsrc = branch ? px : x;
    const float* __restrict__ Ws   = branch ? pW : hW;
    const float* __restrict__ bias = branch ? pb : hb;
    const int nmacro = ((z & 15) == 0) ? 33 : 32;

    // ---- stage x tile 256b x 32i -> half, stride 40 ----
#pragma unroll
    for (int k = 0; k < 4; ++k) {
        int idx = k * 512 + t;              // 0..2047
        int bb = idx >> 3, c = (idx & 7) * 4;
        float4 v = *(const float4*)(xsrc + (b0 + bb) * 512 + ic0 + c);
        *(unsigned*)&xhl[bb * 40 + c]     = pk2(v.x, v.y);
        *(unsigned*)&xhl[bb * 40 + c + 2] = pk2(v.z, v.w);
    }
    // ---- stage noise 256b x 128n -> half into Bl overlay, stride 136 ----
    _Float16* nzl = &Bl[0][0];
#pragma unroll
    for (int k = 0; k < 16; ++k) {
        int idx = k * 512 + t;              // 0..8191
        int bb = idx >> 5, c = (idx & 31) * 4;
        float4 v = *(const float4*)(noise + (b0 + bb) * 128 + c);
        *(unsigned*)&nzl[bb * 136 + c]     = pk2(v.x, v.y);
        *(unsigned*)&nzl[bb * 136 + c + 2] = pk2(v.z, v.w);
    }
    __syncthreads();

    const int lane = t & 63;
    const int w    = t >> 6;
    const int wm64 = (w >> 1) * 64;         // 0,64,128,192
    const int wn64 = (w & 1) * 64;          // 0,64
    const int quad = lane >> 4;
    const int l16  = lane & 15;

    // noise A-fragments in registers: nzf[mf][q][j] = nz_h[row][q*32+quad*8+j]
    half8 nzf[4][4];
#pragma unroll
    for (int mf = 0; mf < 4; ++mf)
#pragma unroll
        for (int q = 0; q < 4; ++q)
            nzf[mf][q] = *(half8*)&nzl[(wm64 + mf * 16 + l16) * 136 + q * 32 + quad * 8];

    floatx4 acc[4][4];
#pragma unroll
    for (int a = 0; a < 4; ++a)
#pragma unroll
        for (int b = 0; b < 4; ++b) acc[a][b] = (floatx4)0.0f;

    // W slab staging: 64KB slab = 128 rows x 128 floats; thread handles 4 chunks
    // of 8 contiguous floats -> one 16B LDS write each (conflict-free minimum).
    float4 wa[4], wb[4];
    {
        const float* p = Ws + (long)(ic0 * 512 + o0) * 128;
#pragma unroll
        for (int j = 0; j < 4; ++j) {
            int c = j * 512 + t;
            int off = (c >> 4) * 128 + (c & 15) * 8;
            wa[j] = *(const float4*)(p + off);
            wb[j] = *(const float4*)(p + off + 4);
        }
    }
    __syncthreads();   // nzf overlay reads complete before first Bl write

    for (int m = 0; m < nmacro; ++m) {
        _Float16* buf = &Bl[m & 1][0];
        // write staged regs -> current buffer (ds_write_b128, lane-consecutive)
#pragma unroll
        for (int j = 0; j < 4; ++j) {
            int c = j * 512 + t;
            int row = c >> 4, col8 = (c & 15) * 8;
            *(uint4*)&buf[row * 136 + col8] = make_uint4(
                pk2(wa[j].x, wa[j].y), pk2(wa[j].z, wa[j].w),
                pk2(wb[j].x, wb[j].y), pk2(wb[j].z, wb[j].w));
        }
        __syncthreads();                     // one barrier per macro (dbuf)
        if (m + 1 < nmacro) {                // prefetch next slab (in flight over MFMA)
            long rb = (m + 1 < 32) ? (long)((ic0 + m + 1) * 512 + o0)
                                   : (long)(MAIN_D + o0);
            const float* p = Ws + rb * 128;
#pragma unroll
            for (int j = 0; j < 4; ++j) {
                int c = j * 512 + t;
                int off = (c >> 4) * 128 + (c & 15) * 8;
                wa[j] = *(const float4*)(p + off);
                wb[j] = *(const float4*)(p + off + 4);
            }
        }
        const bool isE2 = (m >= 32);
        _Float16 xs[4];
        if (!isE2) {
#pragma unroll
            for (int mf = 0; mf < 4; ++mf)
                xs[mf] = xhl[(wm64 + mf * 16 + l16) * 40 + m];
        }
#pragma unroll
        for (int q = 0; q < 4; ++q) {
            half8 bfr[4], afr[4];
#pragma unroll
            for (int nf = 0; nf < 4; ++nf)
                bfr[nf] = *(half8*)&buf[(wn64 + nf * 16 + l16) * 136 + q * 32 + quad * 8];
#pragma unroll
            for (int mf = 0; mf < 4; ++mf) {
                if (isE2) afr[mf] = nzf[mf][q];
                else {
                    half8 xv;
#pragma unroll
                    for (int j = 0; j < 8; ++j) xv[j] = xs[mf];
                    afr[mf] = nzf[mf][q] * xv;
                }
            }
#pragma unroll
            for (int mf = 0; mf < 4; ++mf)
#pragma unroll
                for (int nf = 0; nf < 4; ++nf)
                    acc[mf][nf] = __builtin_amdgcn_mfma_f32_16x16x32_f16(
                        afr[mf], bfr[nf], acc[mf][nf], 0, 0, 0);
        }
    }

    // ---- E1: bias GEMM step, K=32 (A = x tile in LDS) ----
    __syncthreads();
    {
        const int oo = t >> 2, kh = (t & 3) * 8;
        float tmp[8];
#pragma unroll
        for (int j = 0; j < 8; ++j)
            tmp[j] = bias[(long)(ic0 + kh + j) * 512 + o0 + oo];
        *(uint4*)&Bl[0][oo * 136 + kh] = make_uint4(
            pk2(tmp[0], tmp[1]), pk2(tmp[2], tmp[3]),
            pk2(tmp[4], tmp[5]), pk2(tmp[6], tmp[7]));
    }
    __syncthreads();
    {
        half8 afr[4], bfr[4];
#pragma unroll
        for (int mf = 0; mf < 4; ++mf)
            afr[mf] = *(half8*)&xhl[(wm64 + mf * 16 + l16) * 40 + quad * 8];
#pragma unroll
        for (int nf = 0; nf < 4; ++nf)
            bfr[nf] = *(half8*)&Bl[0][(wn64 + nf * 16 + l16) * 136 + quad * 8];
#pragma unroll
        for (int mf = 0; mf < 4; ++mf)
#pragma unroll
            for (int nf = 0; nf < 4; ++nf)
                acc[mf][nf] = __builtin_amdgcn_mfma_f32_16x16x32_f16(
                    afr[mf], bfr[nf], acc[mf][nf], 0, 0, 0);
    }

    // ---- split-K partials: plain stores, unique writer per ws element ----
    // (C/D: row=quad*4+r, col=l16; verified R1/R2)
    float* wsl = ws + (long)z * (512 * 512);
#pragma unroll
    for (int mf = 0; mf < 4; ++mf)
#pragma unroll
        for (int nf = 0; nf < 4; ++nf)
#pragma unroll
            for (int r = 0; r < 4; ++r) {
                int row = b0 + wm64 + mf * 16 + quad * 4 + r;
                int col = o0 + wn64 + nf * 16 + l16;
                wsl[row * 512 + col] = acc[mf][nf][r];
            }
}

extern "C" void kernel_launch(void* const* d_in, const int* in_sizes, int n_in,
                              void* d_out, int out_size, void* d_ws, size_t ws_size,
                              hipStream_t stream) {
    const float* x  = (const float*)d_in[0];
    const float* px = (const float*)d_in[1];
    const float* nz = (const float*)d_in[2];
    const float* hW = (const float*)d_in[3];
    const float* hb = (const float*)d_in[4];
    const float* pW = (const float*)d_in[5];
    const float* pb = (const float*)d_in[6];
    float* out = (float*)d_out;
    float* ws  = (float*)d_ws;   // 32 slices x 1MB = 32MB split-K partials

    hipLaunchKernelGGL(main_gemm, dim3(256), dim3(512), 0, stream,
                       x, px, nz, hW, hb, pW, pb, ws);
    hipLaunchKernelGGL(reduce_kernel, dim3(256), dim3(256), 0, stream,
                       ws, hb, pb, out);
}